// Round 17
// baseline (349.716 us; speedup 1.0000x reference)
//
#include <hip/hip_runtime.h>
#include <hip/hip_bf16.h>
#include <stdint.h>

#define BATCH 8
#define SEQ 2048
#define DMODEL 1024

typedef __attribute__((ext_vector_type(4))) float f32x4;
typedef __attribute__((ext_vector_type(8))) short bf16x8;
typedef __attribute__((ext_vector_type(4))) uint32_t u32x4;
typedef __attribute__((ext_vector_type(2))) uint32_t u32x2;

#define MFMA16(a, b, c) __builtin_amdgcn_mfma_f32_16x16x32_bf16((a), (b), (c), 0, 0, 0)

// ---------------------------------------------------------------------------
// PK ("panel-k-major") operand layout for ALL bf16 GEMM operands:
//   elem(r,k) at offset (r>>4)*(Kd*16) + (k>>3)*128 + (r&15)*8 + (k&7)
//  * staging is contiguous + lane-linear in LDS (global_load_lds-legal);
//  * fragment ds_read_b128 is lane-linear -> zero bank conflicts;
//  * a 16-row panel is a CONTIGUOUS 16K-elem block (32 KB) -> cast kernels
//    can write whole panels with linear stores.
// ---------------------------------------------------------------------------

static __device__ __forceinline__ uint16_t f2bf(float f) {
    uint32_t u = __builtin_bit_cast(uint32_t, f);
    u += 0x7fffu + ((u >> 16) & 1u);   // round-to-nearest-even
    return (uint16_t)(u >> 16);
}
static __device__ __forceinline__ uint32_t pk2(float lo, float hi) {
    return (uint32_t)f2bf(lo) | ((uint32_t)f2bf(hi) << 16);
}
// async global->LDS, 16B per lane. LDS dest is wave-uniform base + lane*16.
static __device__ __forceinline__ void gload16(const uint16_t* g, uint16_t* l) {
    __builtin_amdgcn_global_load_lds((const __attribute__((address_space(1))) void*)g,
                                     (__attribute__((address_space(3))) void*)l, 16, 0, 0);
}

// ---------------------------------------------------------------------------
// Kernel 0 (r17 rewrite): f32 row-major -> bf16 PK cast via LDS transpose.
// One block per 16x1024 panel.  Read side: fully linear/coalesced (wave reads
// 2KB contiguous).  LDS holds the PK image with XOR swizzle row^=(kc&15)
// (both LDS write and read are <=2-way bank aliased = free, m136).  Write
// side: linear 32KB panel dump (PK panels are contiguous).  Same pk2
// rounding + placement as before -> bit-identical downstream.
// blockIdx.y selects input/output pair; destinations DISJOINT.
// ---------------------------------------------------------------------------
__global__ __launch_bounds__(256) void cast3_pk_lds(const float* __restrict__ x0,
                                                    const float* __restrict__ x1,
                                                    const float* __restrict__ x2,
                                                    uint16_t* __restrict__ d0,
                                                    uint16_t* __restrict__ d1,
                                                    uint16_t* __restrict__ d2) {
    const int z = blockIdx.y;
    const float* src = (z == 0 ? x0 : (z == 1 ? x1 : x2)) + (size_t)blockIdx.x * 16384;
    uint16_t* dst = (z == 0 ? d0 : (z == 1 ? d1 : d2)) + (size_t)blockIdx.x * 16384;
    __shared__ __align__(16) uint16_t tile[16384];   // 32 KB PK image (swizzled)
    const int t = threadIdx.x;
#pragma unroll
    for (int i = 0; i < 8; i++) {
        const int c = t + i * 256;                 // chunk of 8 f32: row-major
        const int row = c >> 7, kc = c & 127;      // c = row*128 + kc
        f32x4 a = *(const f32x4*)(src + (size_t)c * 8);
        f32x4 b = *(const f32x4*)(src + (size_t)c * 8 + 4);
        u32x4 o = {pk2(a[0], a[1]), pk2(a[2], a[3]), pk2(b[0], b[1]), pk2(b[2], b[3])};
        *(u32x4*)&tile[kc * 128 + ((row ^ (kc & 15)) * 8)] = o;
    }
    __syncthreads();
#pragma unroll
    for (int i = 0; i < 8; i++) {
        const int c = t + i * 256;                 // linear PK chunk: ks2*16 + r8
        const int ks2 = c >> 4, r8 = c & 15;
        *(u32x4*)(dst + (size_t)c * 8) =
            *(const u32x4*)&tile[ks2 * 128 + ((r8 ^ (ks2 & 15)) * 8)];
    }
}

// ---------------------------------------------------------------------------
// Kernel 1: cast + transpose weights into PK.  WT_pk(n,k) = W[k][n].
// ---------------------------------------------------------------------------
__global__ void wt_cast_kernel(const float* __restrict__ Wk, const float* __restrict__ Wv,
                               const float* __restrict__ Wq, uint16_t* __restrict__ WT) {
    const float* W = blockIdx.z == 0 ? Wk : (blockIdx.z == 1 ? Wv : Wq);
    uint16_t* dst = WT + (size_t)blockIdx.z * DMODEL * DMODEL;
    __shared__ float tile[32][33];
    const int x = blockIdx.x * 32, y = blockIdx.y * 32;
    const int tx = threadIdx.x, ty = threadIdx.y;
#pragma unroll
    for (int j = 0; j < 4; j++)
        tile[ty * 4 + j][tx] = W[(size_t)(y + ty * 4 + j) * DMODEL + x + tx];
    __syncthreads();
#pragma unroll
    for (int j = 0; j < 4; j++) {
        const int n = x + ty * 4 + j, k = y + tx;
        const size_t off = ((size_t)(n >> 4) * (DMODEL / 8) + (k >> 3)) * 128 +
                           (n & 15) * 8 + (k & 7);
        dst[off] = f2bf(tile[tx][ty * 4 + j]);
    }
}

// ---------------------------------------------------------------------------
// Kernel 2: DEEP-PIPELINED 256x256 B^T GEMM, BK=64, 8 waves (2M x 4N),
// 160 KB LDS: As[3 slots] (A staged 2 K-tiles ahead) + Bs[2 slots], PK ops.
//   C[b][m][n] = sum_k A[b][m][k] * Bt[b][n][k]
// COMPILER-SCHEDULED phase bodies: no explicit lgkmcnt/sched_barrier in
// phases (compiler emits fine-grained counted lgkmcnt, m97); zero-instruction
// compiler fences at barriers/vm-waits pin memory ORDER only.
// 1 K-tile per iteration, 4 phases:
//   pre : READ_B(sb)  (8 ds_read_b128; B(kt), staged last iter)
//   ph1 : 4 A-reads q0 | STG B(kt+1)h0 -> Bs[sb^1] | 16 MFMA
//   ph2 : q1           | STG B(kt+1)h1             | 16 MFMA
//   ph3 : q2           | STG A(kt+2)h0 -> As[sa2]  | 16 MFMA
//   ph4 : q3           | STG A(kt+2)h1 | vmcnt(4) | BAR | 16 MFMA | BAR
// vmcnt(4)@ph4 lands A(kt+1)+B(kt+1), keeps A(kt+2) flying.  Slot ledger
// r13-verified (bit-exact).
// MODE 0: bf16 C in PK * scale. MODE 1: bf16 VT store (PK over [e][s]).
// MODE 2: f32 plain C * Linv[row].  MODE 3: merged QKV projection.
// BX=1: batch on blockIdx.x (XCD=batch).
// ---------------------------------------------------------------------------
#define STG_A(kt, sl, h)                                                          \
    do {                                                                          \
        const size_t g0 = (size_t)((h) * 8 + (tid >> 7)) * eldA +                 \
                          (size_t)(kt) * 1024 + (tid & 127) * 8;                  \
        gload16(Ab + g0, &As[sl][(h) * 8192 + tid * 8]);                          \
        gload16(Ab + g0 + 4 * eldA, &As[sl][(h) * 8192 + tid * 8 + 4096]);        \
    } while (0)
#define STG_B(kt, sl, h)                                                          \
    do {                                                                          \
        const size_t g0 = (size_t)((h) * 8 + (tid >> 7)) * eldB +                 \
                          (size_t)(kt) * 1024 + (tid & 127) * 8;                  \
        gload16(Bb + g0, &Bs[sl][(h) * 8192 + tid * 8]);                          \
        gload16(Bb + g0 + 4 * eldB, &Bs[sl][(h) * 8192 + tid * 8 + 4096]);        \
    } while (0)

#define READ_B(sl)                                                                \
    _Pragma("unroll") for (int j = 0; j < 4; j++) {                               \
        bfr[j][0] = *(const bf16x8*)&Bs[sl][(wc * 4 + j) * 1024 + lbase];         \
        bfr[j][1] = *(const bf16x8*)&Bs[sl][(wc * 4 + j) * 1024 + 512 + lbase];   \
    }

#define VM4 asm volatile("s_waitcnt vmcnt(4)" ::: "memory")
#define VM0 asm volatile("s_waitcnt vmcnt(0)" ::: "memory")
#define CFENCE asm volatile("" ::: "memory")
#define NOPW (void)0
#define NOST (void)0

#define MFMA_Q(q)                                                                 \
    __builtin_amdgcn_s_setprio(1);                                                \
    _Pragma("unroll") for (int j = 0; j < 4; j++) {                               \
        acc[2 * (q)][j] = MFMA16(a00, bfr[j][0], acc[2 * (q)][j]);                \
        acc[2 * (q)][j] = MFMA16(a01, bfr[j][1], acc[2 * (q)][j]);                \
        acc[2 * (q) + 1][j] = MFMA16(a10, bfr[j][0], acc[2 * (q) + 1][j]);        \
        acc[2 * (q) + 1][j] = MFMA16(a11, bfr[j][1], acc[2 * (q) + 1][j]);        \
    }                                                                             \
    __builtin_amdgcn_s_setprio(0);

#define PH_FREE(sl, q, STG)                                                       \
    do {                                                                          \
        const int ab = (wr * 8 + 2 * (q)) * 1024 + lbase;                         \
        bf16x8 a00 = *(const bf16x8*)&As[sl][ab];                                 \
        bf16x8 a01 = *(const bf16x8*)&As[sl][ab + 512];                           \
        bf16x8 a10 = *(const bf16x8*)&As[sl][ab + 1024];                          \
        bf16x8 a11 = *(const bf16x8*)&As[sl][ab + 1536];                          \
        STG;                                                                      \
        MFMA_Q(q)                                                                 \
    } while (0)

#define PH_SYNC(sl, q, STG, WAIT)                                                 \
    do {                                                                          \
        const int ab = (wr * 8 + 2 * (q)) * 1024 + lbase;                         \
        bf16x8 a00 = *(const bf16x8*)&As[sl][ab];                                 \
        bf16x8 a01 = *(const bf16x8*)&As[sl][ab + 512];                           \
        bf16x8 a10 = *(const bf16x8*)&As[sl][ab + 1024];                          \
        bf16x8 a11 = *(const bf16x8*)&As[sl][ab + 1536];                          \
        STG;                                                                      \
        WAIT;                                                                     \
        CFENCE;                                                                   \
        __builtin_amdgcn_s_barrier();                                             \
        CFENCE;                                                                   \
        MFMA_Q(q)                                                                 \
        CFENCE;                                                                   \
        __builtin_amdgcn_s_barrier();                                             \
        CFENCE;                                                                   \
    } while (0)

template <int MODE, int BX>
__global__ __launch_bounds__(512, 2) void gemm8p(const uint16_t* __restrict__ Ag,
                                                 const uint16_t* __restrict__ Bg,
                                                 void* __restrict__ Cg,
                                                 const float* __restrict__ Linv,
                                                 float scale, int lda, int ldb, int ldc,
                                                 int nk, size_t sA, size_t sB, size_t sC,
                                                 const uint16_t* __restrict__ A2,
                                                 const uint16_t* __restrict__ A3,
                                                 void* __restrict__ C2,
                                                 void* __restrict__ C3) {
    __shared__ __align__(16) uint16_t As[3][16384];   // 96 KB (3-slot rotation)
    __shared__ __align__(16) uint16_t Bs[2][16384];   // 64 KB -> 160 KB total
    const int bz = BX ? blockIdx.x : blockIdx.z;
    const int bm = BX ? blockIdx.y : blockIdx.x;
    const int bn = BX ? blockIdx.z : blockIdx.y;
    const int m0 = bm * 256, n0 = bn * 256;
    const uint16_t *Abase, *Bbase;
    if constexpr (MODE == 3) {
        // merged projection: bz = 0(Q) / 1(K) / 2(V); WT order in memory: K,V,Q
        Abase = (bz == 0) ? Ag : (bz == 1) ? A2 : A3;
        Bbase = Bg + ((bz == 0) ? 2 * sB : (bz == 1) ? (size_t)0 : sB);
    } else {
        Abase = Ag + (size_t)bz * sA;
        Bbase = Bg + (size_t)bz * sB;
    }
    const uint16_t* Ab = Abase + (size_t)m0 * lda;  // PK panel base
    const uint16_t* Bb = Bbase + (size_t)n0 * ldb;
    const int tid = threadIdx.x, lane = tid & 63;
    const int wid = tid >> 6, wr = wid >> 2, wc = wid & 3;
    const int lr = lane & 15, lg = lane >> 4;
    const int lbase = lg * 128 + lr * 8;
    const size_t eldA = (size_t)lda * 16, eldB = (size_t)ldb * 16;

    f32x4 acc[8][4] = {};
    bf16x8 bfr[4][2];
    // prologue: A(0)->As[0], B(0)->Bs[0], A(1)->As[1]; vmcnt(4) drains
    // A(0)+B(0), leaves A(1) in flight.
    STG_A(0, 0, 0); STG_A(0, 0, 1);
    STG_B(0, 0, 0); STG_B(0, 0, 1);
    STG_A(1, 1, 0); STG_A(1, 1, 1);
    VM4;
    CFENCE;
    __builtin_amdgcn_s_barrier();
    CFENCE;
    int sa = 0, sa2 = 2, sb = 0;   // sa=kt%3, sa2=(kt+2)%3, sb=kt&1
    for (int kt = 0; kt < nk - 2; ++kt) {
        READ_B(sb);
        PH_FREE(sa, 0, STG_B(kt + 1, sb ^ 1, 0));
        PH_FREE(sa, 1, STG_B(kt + 1, sb ^ 1, 1));
        PH_FREE(sa, 2, STG_A(kt + 2, sa2, 0));
        PH_SYNC(sa, 3, STG_A(kt + 2, sa2, 1), VM4);
        sa = (sa == 2) ? 0 : sa + 1;
        sa2 = (sa2 == 2) ? 0 : sa2 + 1;
        sb ^= 1;
    }
    // kt = nk-2: stage last B only; drain everything for the final tile.
    READ_B(sb);
    PH_FREE(sa, 0, STG_B(nk - 1, sb ^ 1, 0));
    PH_FREE(sa, 1, STG_B(nk - 1, sb ^ 1, 1));
    PH_FREE(sa, 2, NOST);
    PH_SYNC(sa, 3, NOST, VM0);
    sa = (sa == 2) ? 0 : sa + 1;
    sb ^= 1;
    // kt = nk-1: no staging, no vm wait.
    READ_B(sb);
    PH_FREE(sa, 0, NOST);
    PH_FREE(sa, 1, NOST);
    PH_FREE(sa, 2, NOST);
    PH_SYNC(sa, 3, NOST, NOPW);

    if constexpr (MODE == 0) {
        uint16_t* C = (uint16_t*)Cg + (size_t)bz * sC;
#pragma unroll
        for (int i = 0; i < 8; i++) {
            const int gm = m0 + wr * 128 + i * 16 + lg * 4;   // gm&15 == lg*4
            const size_t pbase = (size_t)(gm >> 4) * (ldc / 8);
#pragma unroll
            for (int j = 0; j < 4; j++) {
                const int gn = n0 + wc * 64 + j * 16 + lr;
                const size_t off = (pbase + (gn >> 3)) * 128 + (gn & 7);
#pragma unroll
                for (int r = 0; r < 4; r++)
                    C[off + (lg * 4 + r) * 8] = f2bf(acc[i][j][r] * scale);
            }
        }
    } else if constexpr (MODE == 1) {
        uint16_t* C = (uint16_t*)Cg;
#pragma unroll
        for (int i = 0; i < 8; i++) {
            const int gm = m0 + wr * 128 + i * 16 + lg * 4;  // global m = b*SEQ + s
            const int bb = gm / SEQ;                         // uniform per block
            const int s0 = gm - bb * SEQ;                    // s0&7 in {0,4}
            uint16_t* Cb = C + (size_t)bb * DMODEL * SEQ;
#pragma unroll
            for (int j = 0; j < 4; j++) {
                const int e = n0 + wc * 64 + j * 16 + lr;
                const size_t off = ((size_t)(e >> 4) * (SEQ / 8) + (s0 >> 3)) * 128 +
                                   (e & 15) * 8 + (s0 & 7);
                u32x2 v = {pk2(acc[i][j][0], acc[i][j][1]), pk2(acc[i][j][2], acc[i][j][3])};
                *(u32x2*)&Cb[off] = v;
            }
        }
    } else if constexpr (MODE == 2) {
        float* C = (float*)Cg + (size_t)bz * sC;
        const float* LB = Linv + bz * SEQ;
#pragma unroll
        for (int i = 0; i < 8; i++) {
            const int gm = m0 + wr * 128 + i * 16 + lg * 4;
            const f32x4 lv = *(const f32x4*)&LB[gm];
#pragma unroll
            for (int j = 0; j < 4; j++) {
                const int gn = n0 + wc * 64 + j * 16 + lr;
#pragma unroll
                for (int r = 0; r < 4; r++)
                    C[(size_t)(gm + r) * ldc + gn] = acc[i][j][r] * lv[r];
            }
        }
    } else {  // MODE 3: merged projection epilogue
        if (bz < 2) {
            uint16_t* C = (uint16_t*)(bz == 0 ? Cg : C2);
            const float sc = bz == 0 ? scale : 1.0f;
#pragma unroll
            for (int i = 0; i < 8; i++) {
                const int gm = m0 + wr * 128 + i * 16 + lg * 4;
                const size_t pbase = (size_t)(gm >> 4) * (ldc / 8);
#pragma unroll
                for (int j = 0; j < 4; j++) {
                    const int gn = n0 + wc * 64 + j * 16 + lr;
                    const size_t off = (pbase + (gn >> 3)) * 128 + (gn & 7);
#pragma unroll
                    for (int r = 0; r < 4; r++)
                        C[off + (lg * 4 + r) * 8] = f2bf(acc[i][j][r] * sc);
                }
            }
        } else {
            uint16_t* C = (uint16_t*)C3;
#pragma unroll
            for (int i = 0; i < 8; i++) {
                const int gm = m0 + wr * 128 + i * 16 + lg * 4;
                const int bb = gm / SEQ;
                const int s0 = gm - bb * SEQ;
                uint16_t* Cb = C + (size_t)bb * DMODEL * SEQ;
#pragma unroll
                for (int j = 0; j < 4; j++) {
                    const int e = n0 + wc * 64 + j * 16 + lr;
                    const size_t off = ((size_t)(e >> 4) * (SEQ / 8) + (s0 >> 3)) * 128 +
                                       (e & 15) * 8 + (s0 & 7);
                    u32x2 v = {pk2(acc[i][j][0], acc[i][j][1]),
                               pk2(acc[i][j][2], acc[i][j][3])};
                    *(u32x2*)&Cb[off] = v;
                }
            }
        }
    }
}

// ---------------------------------------------------------------------------
// Kernel 3: row softmax on PK-layout S, in place.  One block per 16-row panel
// (contiguous 32KB).  Thread t owns row t&15, k-slots (t>>4)+16u, u=0..15.
// ---------------------------------------------------------------------------
__global__ __launch_bounds__(256) void softmax_pk(uint16_t* __restrict__ S,
                                                  float* __restrict__ Linv) {
    const size_t panel = blockIdx.x;
    uint16_t* sp = S + panel * (size_t)(16 * SEQ);
    const int t = threadIdx.x, lane = t & 63, w = t >> 6;
    const int r15 = t & 15, ksl = t >> 4;
    __shared__ float rm[4][16], rs[4][16];
    u32x4 raw[16];
    float mx = -3.0e38f;
#pragma unroll
    for (int u = 0; u < 16; u++) {
        raw[u] = *(const u32x4*)&sp[(ksl + u * 16) * 128 + r15 * 8];
#pragma unroll
        for (int j = 0; j < 4; j++) {
            mx = fmaxf(mx, __builtin_bit_cast(float, raw[u][j] << 16));
            mx = fmaxf(mx, __builtin_bit_cast(float, raw[u][j] & 0xffff0000u));
        }
    }
    mx = fmaxf(mx, __shfl_xor(mx, 16));
    mx = fmaxf(mx, __shfl_xor(mx, 32));
    if (lane < 16) rm[w][lane] = mx;
    __syncthreads();
    const float m = fmaxf(fmaxf(rm[0][r15], rm[1][r15]), fmaxf(rm[2][r15], rm[3][r15]));
    float sum = 0.0f;
#pragma unroll
    for (int u = 0; u < 16; u++) {
#pragma unroll
        for (int j = 0; j < 4; j++) {
            float lo = __expf(__builtin_bit_cast(float, raw[u][j] << 16) - m);
            float hi = __expf(__builtin_bit_cast(float, raw[u][j] & 0xffff0000u) - m);
            sum += lo + hi;
            raw[u][j] = pk2(lo, hi);
        }
    }
    sum += __shfl_xor(sum, 16);
    sum += __shfl_xor(sum, 32);
    if (lane < 16) rs[w][lane] = sum;
    __syncthreads();
    const float tot = rs[0][r15] + rs[1][r15] + rs[2][r15] + rs[3][r15];
#pragma unroll
    for (int u = 0; u < 16; u++)
        *(u32x4*)&sp[(ksl + u * 16) * 128 + r15 * 8] = raw[u];
    if (w == 0 && lane < 16) Linv[panel * 16 + lane] = 1.0f / tot;
}

// ---------------------------------------------------------------------------
// Buffer plan (aliasing-audited):
//   ws:  Qbf [0, 33.5M)  Kbf [33.5M, 67.1M)  VTb [67.1M, 100.7M)
//        WT  [100.7M, 106.95M)  Linv [106.95M, ~107M)
//        S/P [107,020,288 .. 174,129,152)
//   X casts (all DISJOINT, dead before their region is re-written):
//        XqB = d_out[0 .. 32M)            (PV writes all of d_out at the end)
//        XkB = S + 0       [107,020,288)  (scores writes S after proj done)
//        XvB = S + 33.5MB  [140,574,720)
//   Temporal chain: cast3 -> proj(reads X*, writes Q/K/VT) -> scores(clobbers
//   XkB/XvB) -> softmax -> PV(clobbers XqB, writes full out).
// ---------------------------------------------------------------------------
extern "C" void kernel_launch(void* const* d_in, const int* in_sizes, int n_in,
                              void* d_out, int out_size, void* d_ws, size_t ws_size,
                              hipStream_t stream) {
    const float* Xk = (const float*)d_in[0];
    const float* Xv = (const float*)d_in[1];
    const float* Xq = (const float*)d_in[2];
    const float* Wk = (const float*)d_in[3];
    const float* Wv = (const float*)d_in[4];
    const float* Wq = (const float*)d_in[5];
    float* out = (float*)d_out;
    char* ws = (char*)d_ws;
    uint16_t* Qbf = (uint16_t*)(ws);
    uint16_t* Kbf = (uint16_t*)(ws + (size_t)33554432);
    uint16_t* VTb = (uint16_t*)(ws + (size_t)67108864);
    uint16_t* WT  = (uint16_t*)(ws + (size_t)100663296);
    float*    Linv= (float*)(ws + (size_t)106954752);
    uint16_t* Sb  = (uint16_t*)(ws + (size_t)107020288);
    uint16_t* XqB = (uint16_t*)d_out;                        // 32 MB of 64 MB out
    uint16_t* XkB = Sb;                                      // S + 0
    uint16_t* XvB = (uint16_t*)(ws + (size_t)140574720);     // S + 32 MB

    wt_cast_kernel<<<dim3(32, 32, 3), dim3(32, 8), 0, stream>>>(Wk, Wv, Wq, WT);
    // all three input casts in one dispatch: coalesced read + LDS-transposed
    // PK write (1024 panels per input)
    cast3_pk_lds<<<dim3(1024, 3), 256, 0, stream>>>(Xq, Xk, Xv, XqB, XkB, XvB);
    // merged Q/K/V projection: z=0 Q (scale 1/32), z=1 K, z=2 V (VT store)
    gemm8p<3, 0><<<dim3(64, 4, 3), 512, 0, stream>>>(
        XqB, WT, (void*)Qbf, nullptr, 0.03125f,
        DMODEL, DMODEL, DMODEL, DMODEL / 64,
        0, (size_t)1048576 /*WT stride*/, 0,
        XkB, XvB, (void*)Kbf, (void*)VTb);
    // scores: S[b][q][k] = Qhat[b] . K[b]^T  (bf16 PK store), XCD = batch
    gemm8p<0, 1><<<dim3(8, 8, 8), 512, 0, stream>>>(
        Qbf, Kbf, (void*)Sb, nullptr, 1.0f,
        DMODEL, DMODEL, SEQ, DMODEL / 64,
        (size_t)SEQ * DMODEL, (size_t)SEQ * DMODEL, (size_t)SEQ * SEQ,
        nullptr, nullptr, nullptr, nullptr);
    // in-place row softmax -> P, Linv
    softmax_pk<<<dim3(BATCH * SEQ / 16), 256, 0, stream>>>(Sb, Linv);
    // Z[b][q][e] = (P[b] . V[b]) * Linv  (f32 plain store)
    gemm8p<2, 1><<<dim3(8, 8, 4), 512, 0, stream>>>(
        Sb, VTb, (void*)out, Linv, 1.0f,
        SEQ, SEQ, DMODEL, SEQ / 64,
        (size_t)SEQ * SEQ, (size_t)DMODEL * SEQ, (size_t)SEQ * DMODEL,
        nullptr, nullptr, nullptr, nullptr);
}

// Round 18
// 343.807 us; speedup vs baseline: 1.0172x; 1.0172x over previous
//
#include <hip/hip_runtime.h>
#include <hip/hip_bf16.h>
#include <stdint.h>

#define BATCH 8
#define SEQ 2048
#define DMODEL 1024

typedef __attribute__((ext_vector_type(4))) float f32x4;
typedef __attribute__((ext_vector_type(8))) short bf16x8;
typedef __attribute__((ext_vector_type(4))) uint32_t u32x4;
typedef __attribute__((ext_vector_type(2))) uint32_t u32x2;

#define MFMA16(a, b, c) __builtin_amdgcn_mfma_f32_16x16x32_bf16((a), (b), (c), 0, 0, 0)

// ---------------------------------------------------------------------------
// PK ("panel-k-major") operand layout for ALL bf16 GEMM operands:
//   elem(r,k) at offset (r>>4)*(Kd*16) + (k>>3)*128 + (r&15)*8 + (k&7)
//  * staging is contiguous + lane-linear in LDS (global_load_lds-legal);
//  * fragment ds_read_b128 is lane-linear -> zero bank conflicts.
// ---------------------------------------------------------------------------

static __device__ __forceinline__ uint16_t f2bf(float f) {
    uint32_t u = __builtin_bit_cast(uint32_t, f);
    u += 0x7fffu + ((u >> 16) & 1u);   // round-to-nearest-even
    return (uint16_t)(u >> 16);
}
static __device__ __forceinline__ uint32_t pk2(float lo, float hi) {
    return (uint32_t)f2bf(lo) | ((uint32_t)f2bf(hi) << 16);
}
// async global->LDS, 16B per lane. LDS dest is wave-uniform base + lane*16.
static __device__ __forceinline__ void gload16(const uint16_t* g, uint16_t* l) {
    __builtin_amdgcn_global_load_lds((const __attribute__((address_space(1))) void*)g,
                                     (__attribute__((address_space(3))) void*)l, 16, 0, 0);
}

// ---------------------------------------------------------------------------
// Kernel 0 (r16 version, restored — r17's LDS variant regressed): f32
// row-major -> bf16 PK cast, all three X inputs in one dispatch.
// Destinations are DISJOINT (XqB in d_out, XkB/XvB in the dead S region).
// ---------------------------------------------------------------------------
__global__ __launch_bounds__(256) void cast3_bf16_pk(const float* __restrict__ x0,
                                                     const float* __restrict__ x1,
                                                     const float* __restrict__ x2,
                                                     uint16_t* __restrict__ d0,
                                                     uint16_t* __restrict__ d1,
                                                     uint16_t* __restrict__ d2) {
    const int z = blockIdx.y;
    const float* src = z == 0 ? x0 : (z == 1 ? x1 : x2);
    uint16_t* dst = z == 0 ? d0 : (z == 1 ? d1 : d2);
    const size_t c = (size_t)blockIdx.x * 256 + threadIdx.x;  // PK chunk id
    const size_t panel = c >> 11;           // 2048 chunks per 16x1024 panel
    const int w = (int)(c & 2047);
    const int ks = w >> 4, r15 = w & 15;
    const float* s = src + (panel * 16 + r15) * DMODEL + ks * 8;
    f32x4 a = *(const f32x4*)s;
    f32x4 b = *(const f32x4*)(s + 4);
    u32x4 o = {pk2(a[0], a[1]), pk2(a[2], a[3]), pk2(b[0], b[1]), pk2(b[2], b[3])};
    *(u32x4*)(dst + c * 8) = o;
}

// ---------------------------------------------------------------------------
// Kernel 1: cast + transpose weights into PK.  WT_pk(n,k) = W[k][n].
// ---------------------------------------------------------------------------
__global__ void wt_cast_kernel(const float* __restrict__ Wk, const float* __restrict__ Wv,
                               const float* __restrict__ Wq, uint16_t* __restrict__ WT) {
    const float* W = blockIdx.z == 0 ? Wk : (blockIdx.z == 1 ? Wv : Wq);
    uint16_t* dst = WT + (size_t)blockIdx.z * DMODEL * DMODEL;
    __shared__ float tile[32][33];
    const int x = blockIdx.x * 32, y = blockIdx.y * 32;
    const int tx = threadIdx.x, ty = threadIdx.y;
#pragma unroll
    for (int j = 0; j < 4; j++)
        tile[ty * 4 + j][tx] = W[(size_t)(y + ty * 4 + j) * DMODEL + x + tx];
    __syncthreads();
#pragma unroll
    for (int j = 0; j < 4; j++) {
        const int n = x + ty * 4 + j, k = y + tx;
        const size_t off = ((size_t)(n >> 4) * (DMODEL / 8) + (k >> 3)) * 128 +
                           (n & 15) * 8 + (k & 7);
        dst[off] = f2bf(tile[tx][ty * 4 + j]);
    }
}

// ---------------------------------------------------------------------------
// Kernel 2: DEEP-PIPELINED 256x256 B^T GEMM, BK=64, 8 waves (2M x 4N),
// 160 KB LDS: As[3 slots] + Bs[2 slots], PK ops.
//   C[b][m][n] = sum_k A[b][m][k] * Bt[b][n][k]
// r18 change: EARLY STAGE GROUPING — both B(kt+1) halves issue at ph1
// (maximal slack before ph4's vmcnt drain; previously h1 issued at ph2 with
// only ~1.5 phases of slack), both A(kt+2) halves at ph3; ph2 is pure MFMA.
// COMPILER-SCHEDULED phase bodies (no explicit lgkm drains); zero-instruction
// compiler fences at barriers/vm-waits pin memory ORDER only.
// 1 K-tile per iteration, 4 phases:
//   pre : READ_B(sb)  (8 ds_read_b128; B(kt), staged last iter)
//   ph1 : 4 A-reads q0 | STG B(kt+1) h0+h1 -> Bs[sb^1] | 16 MFMA
//   ph2 : q1           | (pure MFMA)                   | 16 MFMA
//   ph3 : q2           | STG A(kt+2) h0+h1 -> As[sa2]  | 16 MFMA
//   ph4 : q3           | vmcnt(4) | BAR | 16 MFMA | BAR
// vmcnt(4)@ph4: outstanding (oldest first) = A(kt+1)[4, prev ph3] +
// B(kt+1)[4, ph1] + A(kt+2)[4, ph3] = 12 -> drain to 4 lands A(kt+1)+B(kt+1)
// (all of next iter's reads), keeps A(kt+2) in flight.
// Slot ledger (unchanged from r13-verified): every overwrite post-dates the
// ENDBAR that retires its slot's readers (B stage at ph1 follows prev
// ENDBAR; A stage at ph3 overwrites As[(kt-1)%3], read through prev iter
// whose ENDBAR precedes this ph3).
// MODE 0: bf16 C in PK * scale. MODE 1: bf16 VT store (PK over [e][s]).
// MODE 2: f32 plain C * Linv[row].  MODE 3: merged QKV projection.
// BX=1: batch on blockIdx.x (XCD=batch).
// ---------------------------------------------------------------------------
#define STG_A2(kt, sl)                                                            \
    do {                                                                          \
        const size_t gA = (size_t)(tid >> 7) * eldA +                             \
                          (size_t)(kt) * 1024 + (tid & 127) * 8;                  \
        gload16(Ab + gA, &As[sl][tid * 8]);                                       \
        gload16(Ab + gA + 4 * eldA, &As[sl][tid * 8 + 4096]);                     \
        gload16(Ab + gA + 8 * eldA, &As[sl][8192 + tid * 8]);                     \
        gload16(Ab + gA + 12 * eldA, &As[sl][8192 + tid * 8 + 4096]);             \
    } while (0)
#define STG_B2(kt, sl)                                                            \
    do {                                                                          \
        const size_t gB = (size_t)(tid >> 7) * eldB +                             \
                          (size_t)(kt) * 1024 + (tid & 127) * 8;                  \
        gload16(Bb + gB, &Bs[sl][tid * 8]);                                       \
        gload16(Bb + gB + 4 * eldB, &Bs[sl][tid * 8 + 4096]);                     \
        gload16(Bb + gB + 8 * eldB, &Bs[sl][8192 + tid * 8]);                     \
        gload16(Bb + gB + 12 * eldB, &Bs[sl][8192 + tid * 8 + 4096]);             \
    } while (0)

#define READ_B(sl)                                                                \
    _Pragma("unroll") for (int j = 0; j < 4; j++) {                               \
        bfr[j][0] = *(const bf16x8*)&Bs[sl][(wc * 4 + j) * 1024 + lbase];         \
        bfr[j][1] = *(const bf16x8*)&Bs[sl][(wc * 4 + j) * 1024 + 512 + lbase];   \
    }

#define VM4 asm volatile("s_waitcnt vmcnt(4)" ::: "memory")
#define VM0 asm volatile("s_waitcnt vmcnt(0)" ::: "memory")
#define CFENCE asm volatile("" ::: "memory")
#define NOPW (void)0
#define NOST (void)0

#define MFMA_Q(q)                                                                 \
    __builtin_amdgcn_s_setprio(1);                                                \
    _Pragma("unroll") for (int j = 0; j < 4; j++) {                               \
        acc[2 * (q)][j] = MFMA16(a00, bfr[j][0], acc[2 * (q)][j]);                \
        acc[2 * (q)][j] = MFMA16(a01, bfr[j][1], acc[2 * (q)][j]);                \
        acc[2 * (q) + 1][j] = MFMA16(a10, bfr[j][0], acc[2 * (q) + 1][j]);        \
        acc[2 * (q) + 1][j] = MFMA16(a11, bfr[j][1], acc[2 * (q) + 1][j]);        \
    }                                                                             \
    __builtin_amdgcn_s_setprio(0);

#define PH_FREE(sl, q, STG)                                                       \
    do {                                                                          \
        const int ab = (wr * 8 + 2 * (q)) * 1024 + lbase;                         \
        bf16x8 a00 = *(const bf16x8*)&As[sl][ab];                                 \
        bf16x8 a01 = *(const bf16x8*)&As[sl][ab + 512];                           \
        bf16x8 a10 = *(const bf16x8*)&As[sl][ab + 1024];                          \
        bf16x8 a11 = *(const bf16x8*)&As[sl][ab + 1536];                          \
        STG;                                                                      \
        MFMA_Q(q)                                                                 \
    } while (0)

#define PH_SYNC(sl, q, WAIT)                                                      \
    do {                                                                          \
        const int ab = (wr * 8 + 2 * (q)) * 1024 + lbase;                         \
        bf16x8 a00 = *(const bf16x8*)&As[sl][ab];                                 \
        bf16x8 a01 = *(const bf16x8*)&As[sl][ab + 512];                           \
        bf16x8 a10 = *(const bf16x8*)&As[sl][ab + 1024];                          \
        bf16x8 a11 = *(const bf16x8*)&As[sl][ab + 1536];                          \
        WAIT;                                                                     \
        CFENCE;                                                                   \
        __builtin_amdgcn_s_barrier();                                             \
        CFENCE;                                                                   \
        MFMA_Q(q)                                                                 \
        CFENCE;                                                                   \
        __builtin_amdgcn_s_barrier();                                             \
        CFENCE;                                                                   \
    } while (0)

template <int MODE, int BX>
__global__ __launch_bounds__(512, 2) void gemm8p(const uint16_t* __restrict__ Ag,
                                                 const uint16_t* __restrict__ Bg,
                                                 void* __restrict__ Cg,
                                                 const float* __restrict__ Linv,
                                                 float scale, int lda, int ldb, int ldc,
                                                 int nk, size_t sA, size_t sB, size_t sC,
                                                 const uint16_t* __restrict__ A2,
                                                 const uint16_t* __restrict__ A3,
                                                 void* __restrict__ C2,
                                                 void* __restrict__ C3) {
    __shared__ __align__(16) uint16_t As[3][16384];   // 96 KB (3-slot rotation)
    __shared__ __align__(16) uint16_t Bs[2][16384];   // 64 KB -> 160 KB total
    const int bz = BX ? blockIdx.x : blockIdx.z;
    const int bm = BX ? blockIdx.y : blockIdx.x;
    const int bn = BX ? blockIdx.z : blockIdx.y;
    const int m0 = bm * 256, n0 = bn * 256;
    const uint16_t *Abase, *Bbase;
    if constexpr (MODE == 3) {
        // merged projection: bz = 0(Q) / 1(K) / 2(V); WT order in memory: K,V,Q
        Abase = (bz == 0) ? Ag : (bz == 1) ? A2 : A3;
        Bbase = Bg + ((bz == 0) ? 2 * sB : (bz == 1) ? (size_t)0 : sB);
    } else {
        Abase = Ag + (size_t)bz * sA;
        Bbase = Bg + (size_t)bz * sB;
    }
    const uint16_t* Ab = Abase + (size_t)m0 * lda;  // PK panel base
    const uint16_t* Bb = Bbase + (size_t)n0 * ldb;
    const int tid = threadIdx.x, lane = tid & 63;
    const int wid = tid >> 6, wr = wid >> 2, wc = wid & 3;
    const int lr = lane & 15, lg = lane >> 4;
    const int lbase = lg * 128 + lr * 8;
    const size_t eldA = (size_t)lda * 16, eldB = (size_t)ldb * 16;

    f32x4 acc[8][4] = {};
    bf16x8 bfr[4][2];
    // prologue: A(0)->As[0], B(0)->Bs[0], A(1)->As[1]; vmcnt(4) drains
    // A(0)+B(0), leaves A(1) in flight.
    STG_A2(0, 0);
    STG_B2(0, 0);
    STG_A2(1, 1);
    VM4;
    CFENCE;
    __builtin_amdgcn_s_barrier();
    CFENCE;
    int sa = 0, sa2 = 2, sb = 0;   // sa=kt%3, sa2=(kt+2)%3, sb=kt&1
    for (int kt = 0; kt < nk - 2; ++kt) {
        READ_B(sb);
        PH_FREE(sa, 0, STG_B2(kt + 1, sb ^ 1));
        PH_FREE(sa, 1, NOST);
        PH_FREE(sa, 2, STG_A2(kt + 2, sa2));
        PH_SYNC(sa, 3, VM4);
        sa = (sa == 2) ? 0 : sa + 1;
        sa2 = (sa2 == 2) ? 0 : sa2 + 1;
        sb ^= 1;
    }
    // kt = nk-2: stage last B only; drain everything for the final tile.
    READ_B(sb);
    PH_FREE(sa, 0, STG_B2(nk - 1, sb ^ 1));
    PH_FREE(sa, 1, NOST);
    PH_FREE(sa, 2, NOST);
    PH_SYNC(sa, 3, VM0);
    sa = (sa == 2) ? 0 : sa + 1;
    sb ^= 1;
    // kt = nk-1: no staging, no vm wait.
    READ_B(sb);
    PH_FREE(sa, 0, NOST);
    PH_FREE(sa, 1, NOST);
    PH_FREE(sa, 2, NOST);
    PH_SYNC(sa, 3, NOPW);

    if constexpr (MODE == 0) {
        uint16_t* C = (uint16_t*)Cg + (size_t)bz * sC;
#pragma unroll
        for (int i = 0; i < 8; i++) {
            const int gm = m0 + wr * 128 + i * 16 + lg * 4;   // gm&15 == lg*4
            const size_t pbase = (size_t)(gm >> 4) * (ldc / 8);
#pragma unroll
            for (int j = 0; j < 4; j++) {
                const int gn = n0 + wc * 64 + j * 16 + lr;
                const size_t off = (pbase + (gn >> 3)) * 128 + (gn & 7);
#pragma unroll
                for (int r = 0; r < 4; r++)
                    C[off + (lg * 4 + r) * 8] = f2bf(acc[i][j][r] * scale);
            }
        }
    } else if constexpr (MODE == 1) {
        uint16_t* C = (uint16_t*)Cg;
#pragma unroll
        for (int i = 0; i < 8; i++) {
            const int gm = m0 + wr * 128 + i * 16 + lg * 4;  // global m = b*SEQ + s
            const int bb = gm / SEQ;                         // uniform per block
            const int s0 = gm - bb * SEQ;                    // s0&7 in {0,4}
            uint16_t* Cb = C + (size_t)bb * DMODEL * SEQ;
#pragma unroll
            for (int j = 0; j < 4; j++) {
                const int e = n0 + wc * 64 + j * 16 + lr;
                const size_t off = ((size_t)(e >> 4) * (SEQ / 8) + (s0 >> 3)) * 128 +
                                   (e & 15) * 8 + (s0 & 7);
                u32x2 v = {pk2(acc[i][j][0], acc[i][j][1]), pk2(acc[i][j][2], acc[i][j][3])};
                *(u32x2*)&Cb[off] = v;
            }
        }
    } else if constexpr (MODE == 2) {
        float* C = (float*)Cg + (size_t)bz * sC;
        const float* LB = Linv + bz * SEQ;
#pragma unroll
        for (int i = 0; i < 8; i++) {
            const int gm = m0 + wr * 128 + i * 16 + lg * 4;
            const f32x4 lv = *(const f32x4*)&LB[gm];
#pragma unroll
            for (int j = 0; j < 4; j++) {
                const int gn = n0 + wc * 64 + j * 16 + lr;
#pragma unroll
                for (int r = 0; r < 4; r++)
                    C[(size_t)(gm + r) * ldc + gn] = acc[i][j][r] * lv[r];
            }
        }
    } else {  // MODE 3: merged projection epilogue
        if (bz < 2) {
            uint16_t* C = (uint16_t*)(bz == 0 ? Cg : C2);
            const float sc = bz == 0 ? scale : 1.0f;
#pragma unroll
            for (int i = 0; i < 8; i++) {
                const int gm = m0 + wr * 128 + i * 16 + lg * 4;
                const size_t pbase = (size_t)(gm >> 4) * (ldc / 8);
#pragma unroll
                for (int j = 0; j < 4; j++) {
                    const int gn = n0 + wc * 64 + j * 16 + lr;
                    const size_t off = (pbase + (gn >> 3)) * 128 + (gn & 7);
#pragma unroll
                    for (int r = 0; r < 4; r++)
                        C[off + (lg * 4 + r) * 8] = f2bf(acc[i][j][r] * sc);
                }
            }
        } else {
            uint16_t* C = (uint16_t*)C3;
#pragma unroll
            for (int i = 0; i < 8; i++) {
                const int gm = m0 + wr * 128 + i * 16 + lg * 4;
                const int bb = gm / SEQ;
                const int s0 = gm - bb * SEQ;
                uint16_t* Cb = C + (size_t)bb * DMODEL * SEQ;
#pragma unroll
                for (int j = 0; j < 4; j++) {
                    const int e = n0 + wc * 64 + j * 16 + lr;
                    const size_t off = ((size_t)(e >> 4) * (SEQ / 8) + (s0 >> 3)) * 128 +
                                       (e & 15) * 8 + (s0 & 7);
                    u32x2 v = {pk2(acc[i][j][0], acc[i][j][1]),
                               pk2(acc[i][j][2], acc[i][j][3])};
                    *(u32x2*)&Cb[off] = v;
                }
            }
        }
    }
}

// ---------------------------------------------------------------------------
// Kernel 3: row softmax on PK-layout S, in place.  One block per 16-row panel
// (contiguous 32KB).  Thread t owns row t&15, k-slots (t>>4)+16u, u=0..15.
// ---------------------------------------------------------------------------
__global__ __launch_bounds__(256) void softmax_pk(uint16_t* __restrict__ S,
                                                  float* __restrict__ Linv) {
    const size_t panel = blockIdx.x;
    uint16_t* sp = S + panel * (size_t)(16 * SEQ);
    const int t = threadIdx.x, lane = t & 63, w = t >> 6;
    const int r15 = t & 15, ksl = t >> 4;
    __shared__ float rm[4][16], rs[4][16];
    u32x4 raw[16];
    float mx = -3.0e38f;
#pragma unroll
    for (int u = 0; u < 16; u++) {
        raw[u] = *(const u32x4*)&sp[(ksl + u * 16) * 128 + r15 * 8];
#pragma unroll
        for (int j = 0; j < 4; j++) {
            mx = fmaxf(mx, __builtin_bit_cast(float, raw[u][j] << 16));
            mx = fmaxf(mx, __builtin_bit_cast(float, raw[u][j] & 0xffff0000u));
        }
    }
    mx = fmaxf(mx, __shfl_xor(mx, 16));
    mx = fmaxf(mx, __shfl_xor(mx, 32));
    if (lane < 16) rm[w][lane] = mx;
    __syncthreads();
    const float m = fmaxf(fmaxf(rm[0][r15], rm[1][r15]), fmaxf(rm[2][r15], rm[3][r15]));
    float sum = 0.0f;
#pragma unroll
    for (int u = 0; u < 16; u++) {
#pragma unroll
        for (int j = 0; j < 4; j++) {
            float lo = __expf(__builtin_bit_cast(float, raw[u][j] << 16) - m);
            float hi = __expf(__builtin_bit_cast(float, raw[u][j] & 0xffff0000u) - m);
            sum += lo + hi;
            raw[u][j] = pk2(lo, hi);
        }
    }
    sum += __shfl_xor(sum, 16);
    sum += __shfl_xor(sum, 32);
    if (lane < 16) rs[w][lane] = sum;
    __syncthreads();
    const float tot = rs[0][r15] + rs[1][r15] + rs[2][r15] + rs[3][r15];
#pragma unroll
    for (int u = 0; u < 16; u++)
        *(u32x4*)&sp[(ksl + u * 16) * 128 + r15 * 8] = raw[u];
    if (w == 0 && lane < 16) Linv[panel * 16 + lane] = 1.0f / tot;
}

// ---------------------------------------------------------------------------
// Buffer plan (aliasing-audited):
//   ws:  Qbf [0, 33.5M)  Kbf [33.5M, 67.1M)  VTb [67.1M, 100.7M)
//        WT  [100.7M, 106.95M)  Linv [106.95M, ~107M)
//        S/P [107,020,288 .. 174,129,152)
//   X casts (all DISJOINT, dead before their region is re-written):
//        XqB = d_out[0 .. 32M)            (PV writes all of d_out at the end)
//        XkB = S + 0       [107,020,288)  (scores writes S after proj done)
//        XvB = S + 33.5MB  [140,574,720)
//   Temporal chain: cast3 -> proj(reads X*, writes Q/K/VT) -> scores(clobbers
//   XkB/XvB) -> softmax -> PV(clobbers XqB, writes full out).
// ---------------------------------------------------------------------------
extern "C" void kernel_launch(void* const* d_in, const int* in_sizes, int n_in,
                              void* d_out, int out_size, void* d_ws, size_t ws_size,
                              hipStream_t stream) {
    const float* Xk = (const float*)d_in[0];
    const float* Xv = (const float*)d_in[1];
    const float* Xq = (const float*)d_in[2];
    const float* Wk = (const float*)d_in[3];
    const float* Wv = (const float*)d_in[4];
    const float* Wq = (const float*)d_in[5];
    float* out = (float*)d_out;
    char* ws = (char*)d_ws;
    uint16_t* Qbf = (uint16_t*)(ws);
    uint16_t* Kbf = (uint16_t*)(ws + (size_t)33554432);
    uint16_t* VTb = (uint16_t*)(ws + (size_t)67108864);
    uint16_t* WT  = (uint16_t*)(ws + (size_t)100663296);
    float*    Linv= (float*)(ws + (size_t)106954752);
    uint16_t* Sb  = (uint16_t*)(ws + (size_t)107020288);
    uint16_t* XqB = (uint16_t*)d_out;                        // 32 MB of 64 MB out
    uint16_t* XkB = Sb;                                      // S + 0
    uint16_t* XvB = (uint16_t*)(ws + (size_t)140574720);     // S + 32 MB

    wt_cast_kernel<<<dim3(32, 32, 3), dim3(32, 8), 0, stream>>>(Wk, Wv, Wq, WT);
    // all three input casts in one dispatch (disjoint destinations)
    cast3_bf16_pk<<<dim3(8192, 3), 256, 0, stream>>>(Xq, Xk, Xv, XqB, XkB, XvB);
    // merged Q/K/V projection: z=0 Q (scale 1/32), z=1 K, z=2 V (VT store)
    gemm8p<3, 0><<<dim3(64, 4, 3), 512, 0, stream>>>(
        XqB, WT, (void*)Qbf, nullptr, 0.03125f,
        DMODEL, DMODEL, DMODEL, DMODEL / 64,
        0, (size_t)1048576 /*WT stride*/, 0,
        XkB, XvB, (void*)Kbf, (void*)VTb);
    // scores: S[b][q][k] = Qhat[b] . K[b]^T  (bf16 PK store), XCD = batch
    gemm8p<0, 1><<<dim3(8, 8, 8), 512, 0, stream>>>(
        Qbf, Kbf, (void*)Sb, nullptr, 1.0f,
        DMODEL, DMODEL, SEQ, DMODEL / 64,
        (size_t)SEQ * DMODEL, (size_t)SEQ * DMODEL, (size_t)SEQ * SEQ,
        nullptr, nullptr, nullptr, nullptr);
    // in-place row softmax -> P, Linv
    softmax_pk<<<dim3(BATCH * SEQ / 16), 256, 0, stream>>>(Sb, Linv);
    // Z[b][q][e] = (P[b] . V[b]) * Linv  (f32 plain store)
    gemm8p<2, 1><<<dim3(8, 8, 4), 512, 0, stream>>>(
        Sb, VTb, (void*)out, Linv, 1.0f,
        SEQ, SEQ, DMODEL, SEQ / 64,
        (size_t)SEQ * SEQ, (size_t)DMODEL * SEQ, (size_t)SEQ * DMODEL,
        nullptr, nullptr, nullptr, nullptr);
}

// Round 19
// 341.103 us; speedup vs baseline: 1.0253x; 1.0079x over previous
//
#include <hip/hip_runtime.h>
#include <hip/hip_bf16.h>
#include <stdint.h>

#define BATCH 8
#define SEQ 2048
#define DMODEL 1024

typedef __attribute__((ext_vector_type(4))) float f32x4;
typedef __attribute__((ext_vector_type(8))) short bf16x8;
typedef __attribute__((ext_vector_type(4))) uint32_t u32x4;
typedef __attribute__((ext_vector_type(2))) uint32_t u32x2;

#define MFMA16(a, b, c) __builtin_amdgcn_mfma_f32_16x16x32_bf16((a), (b), (c), 0, 0, 0)

// ---------------------------------------------------------------------------
// PK ("panel-k-major") operand layout for ALL bf16 GEMM operands:
//   elem(r,k) at offset (r>>4)*(Kd*16) + (k>>3)*128 + (r&15)*8 + (k&7)
//  * staging is contiguous + lane-linear in LDS (global_load_lds-legal);
//  * fragment ds_read_b128 is lane-linear -> zero bank conflicts.
// This source is the exact r16 state (session-best, 339.1 us) — reverted
// after r17/r18 experiments regressed.
// ---------------------------------------------------------------------------

static __device__ __forceinline__ uint16_t f2bf(float f) {
    uint32_t u = __builtin_bit_cast(uint32_t, f);
    u += 0x7fffu + ((u >> 16) & 1u);   // round-to-nearest-even
    return (uint16_t)(u >> 16);
}
static __device__ __forceinline__ uint32_t pk2(float lo, float hi) {
    return (uint32_t)f2bf(lo) | ((uint32_t)f2bf(hi) << 16);
}
// async global->LDS, 16B per lane. LDS dest is wave-uniform base + lane*16.
static __device__ __forceinline__ void gload16(const uint16_t* g, uint16_t* l) {
    __builtin_amdgcn_global_load_lds((const __attribute__((address_space(1))) void*)g,
                                     (__attribute__((address_space(3))) void*)l, 16, 0, 0);
}

// ---------------------------------------------------------------------------
// Kernel 0: f32 row-major -> bf16 PK cast, all three X inputs in one dispatch.
// Destinations are DISJOINT (XqB in d_out, XkB/XvB in the dead S region).
// ---------------------------------------------------------------------------
__global__ __launch_bounds__(256) void cast3_bf16_pk(const float* __restrict__ x0,
                                                     const float* __restrict__ x1,
                                                     const float* __restrict__ x2,
                                                     uint16_t* __restrict__ d0,
                                                     uint16_t* __restrict__ d1,
                                                     uint16_t* __restrict__ d2) {
    const int z = blockIdx.y;
    const float* src = z == 0 ? x0 : (z == 1 ? x1 : x2);
    uint16_t* dst = z == 0 ? d0 : (z == 1 ? d1 : d2);
    const size_t c = (size_t)blockIdx.x * 256 + threadIdx.x;  // PK chunk id
    const size_t panel = c >> 11;           // 2048 chunks per 16x1024 panel
    const int w = (int)(c & 2047);
    const int ks = w >> 4, r15 = w & 15;
    const float* s = src + (panel * 16 + r15) * DMODEL + ks * 8;
    f32x4 a = *(const f32x4*)s;
    f32x4 b = *(const f32x4*)(s + 4);
    u32x4 o = {pk2(a[0], a[1]), pk2(a[2], a[3]), pk2(b[0], b[1]), pk2(b[2], b[3])};
    *(u32x4*)(dst + c * 8) = o;
}

// ---------------------------------------------------------------------------
// Kernel 1: cast + transpose weights into PK.  WT_pk(n,k) = W[k][n].
// ---------------------------------------------------------------------------
__global__ void wt_cast_kernel(const float* __restrict__ Wk, const float* __restrict__ Wv,
                               const float* __restrict__ Wq, uint16_t* __restrict__ WT) {
    const float* W = blockIdx.z == 0 ? Wk : (blockIdx.z == 1 ? Wv : Wq);
    uint16_t* dst = WT + (size_t)blockIdx.z * DMODEL * DMODEL;
    __shared__ float tile[32][33];
    const int x = blockIdx.x * 32, y = blockIdx.y * 32;
    const int tx = threadIdx.x, ty = threadIdx.y;
#pragma unroll
    for (int j = 0; j < 4; j++)
        tile[ty * 4 + j][tx] = W[(size_t)(y + ty * 4 + j) * DMODEL + x + tx];
    __syncthreads();
#pragma unroll
    for (int j = 0; j < 4; j++) {
        const int n = x + ty * 4 + j, k = y + tx;
        const size_t off = ((size_t)(n >> 4) * (DMODEL / 8) + (k >> 3)) * 128 +
                           (n & 15) * 8 + (k & 7);
        dst[off] = f2bf(tile[tx][ty * 4 + j]);
    }
}

// ---------------------------------------------------------------------------
// Kernel 2: DEEP-PIPELINED 256x256 B^T GEMM, BK=64, 8 waves (2M x 4N),
// 160 KB LDS: As[3 slots] (A staged 2 K-tiles ahead) + Bs[2 slots], PK ops.
//   C[b][m][n] = sum_k A[b][m][k] * Bt[b][n][k]
// COMPILER-SCHEDULED phase bodies: no explicit lgkmcnt/sched_barrier in
// phases (compiler emits fine-grained counted lgkmcnt, m97); zero-instruction
// compiler fences at barriers/vm-waits pin memory ORDER only.
// 1 K-tile per iteration, 4 phases:
//   pre : READ_B(sb)  (8 ds_read_b128; B(kt), staged last iter)
//   ph1 : 4 A-reads q0 | STG B(kt+1)h0 -> Bs[sb^1] | 16 MFMA
//   ph2 : q1           | STG B(kt+1)h1             | 16 MFMA
//   ph3 : q2           | STG A(kt+2)h0 -> As[sa2]  | 16 MFMA
//   ph4 : q3           | STG A(kt+2)h1 | vmcnt(4) | BAR | 16 MFMA | BAR
// vmcnt(4)@ph4 lands A(kt+1)+B(kt+1), keeps A(kt+2) flying.  Slot ledger
// r13-verified (bit-exact).
// MODE 0: bf16 C in PK * scale. MODE 1: bf16 VT store (PK over [e][s]).
// MODE 2: f32 plain C * Linv[row].  MODE 3: merged QKV projection.
// BX=1: batch on blockIdx.x (XCD=batch).
// ---------------------------------------------------------------------------
#define STG_A(kt, sl, h)                                                          \
    do {                                                                          \
        const size_t g0 = (size_t)((h) * 8 + (tid >> 7)) * eldA +                 \
                          (size_t)(kt) * 1024 + (tid & 127) * 8;                  \
        gload16(Ab + g0, &As[sl][(h) * 8192 + tid * 8]);                          \
        gload16(Ab + g0 + 4 * eldA, &As[sl][(h) * 8192 + tid * 8 + 4096]);        \
    } while (0)
#define STG_B(kt, sl, h)                                                          \
    do {                                                                          \
        const size_t g0 = (size_t)((h) * 8 + (tid >> 7)) * eldB +                 \
                          (size_t)(kt) * 1024 + (tid & 127) * 8;                  \
        gload16(Bb + g0, &Bs[sl][(h) * 8192 + tid * 8]);                          \
        gload16(Bb + g0 + 4 * eldB, &Bs[sl][(h) * 8192 + tid * 8 + 4096]);        \
    } while (0)

#define READ_B(sl)                                                                \
    _Pragma("unroll") for (int j = 0; j < 4; j++) {                               \
        bfr[j][0] = *(const bf16x8*)&Bs[sl][(wc * 4 + j) * 1024 + lbase];         \
        bfr[j][1] = *(const bf16x8*)&Bs[sl][(wc * 4 + j) * 1024 + 512 + lbase];   \
    }

#define VM4 asm volatile("s_waitcnt vmcnt(4)" ::: "memory")
#define VM0 asm volatile("s_waitcnt vmcnt(0)" ::: "memory")
#define CFENCE asm volatile("" ::: "memory")
#define NOPW (void)0
#define NOST (void)0

#define MFMA_Q(q)                                                                 \
    __builtin_amdgcn_s_setprio(1);                                                \
    _Pragma("unroll") for (int j = 0; j < 4; j++) {                               \
        acc[2 * (q)][j] = MFMA16(a00, bfr[j][0], acc[2 * (q)][j]);                \
        acc[2 * (q)][j] = MFMA16(a01, bfr[j][1], acc[2 * (q)][j]);                \
        acc[2 * (q) + 1][j] = MFMA16(a10, bfr[j][0], acc[2 * (q) + 1][j]);        \
        acc[2 * (q) + 1][j] = MFMA16(a11, bfr[j][1], acc[2 * (q) + 1][j]);        \
    }                                                                             \
    __builtin_amdgcn_s_setprio(0);

#define PH_FREE(sl, q, STG)                                                       \
    do {                                                                          \
        const int ab = (wr * 8 + 2 * (q)) * 1024 + lbase;                         \
        bf16x8 a00 = *(const bf16x8*)&As[sl][ab];                                 \
        bf16x8 a01 = *(const bf16x8*)&As[sl][ab + 512];                           \
        bf16x8 a10 = *(const bf16x8*)&As[sl][ab + 1024];                          \
        bf16x8 a11 = *(const bf16x8*)&As[sl][ab + 1536];                          \
        STG;                                                                      \
        MFMA_Q(q)                                                                 \
    } while (0)

#define PH_SYNC(sl, q, STG, WAIT)                                                 \
    do {                                                                          \
        const int ab = (wr * 8 + 2 * (q)) * 1024 + lbase;                         \
        bf16x8 a00 = *(const bf16x8*)&As[sl][ab];                                 \
        bf16x8 a01 = *(const bf16x8*)&As[sl][ab + 512];                           \
        bf16x8 a10 = *(const bf16x8*)&As[sl][ab + 1024];                          \
        bf16x8 a11 = *(const bf16x8*)&As[sl][ab + 1536];                          \
        STG;                                                                      \
        WAIT;                                                                     \
        CFENCE;                                                                   \
        __builtin_amdgcn_s_barrier();                                             \
        CFENCE;                                                                   \
        MFMA_Q(q)                                                                 \
        CFENCE;                                                                   \
        __builtin_amdgcn_s_barrier();                                             \
        CFENCE;                                                                   \
    } while (0)

template <int MODE, int BX>
__global__ __launch_bounds__(512, 2) void gemm8p(const uint16_t* __restrict__ Ag,
                                                 const uint16_t* __restrict__ Bg,
                                                 void* __restrict__ Cg,
                                                 const float* __restrict__ Linv,
                                                 float scale, int lda, int ldb, int ldc,
                                                 int nk, size_t sA, size_t sB, size_t sC,
                                                 const uint16_t* __restrict__ A2,
                                                 const uint16_t* __restrict__ A3,
                                                 void* __restrict__ C2,
                                                 void* __restrict__ C3) {
    __shared__ __align__(16) uint16_t As[3][16384];   // 96 KB (3-slot rotation)
    __shared__ __align__(16) uint16_t Bs[2][16384];   // 64 KB -> 160 KB total
    const int bz = BX ? blockIdx.x : blockIdx.z;
    const int bm = BX ? blockIdx.y : blockIdx.x;
    const int bn = BX ? blockIdx.z : blockIdx.y;
    const int m0 = bm * 256, n0 = bn * 256;
    const uint16_t *Abase, *Bbase;
    if constexpr (MODE == 3) {
        // merged projection: bz = 0(Q) / 1(K) / 2(V); WT order in memory: K,V,Q
        Abase = (bz == 0) ? Ag : (bz == 1) ? A2 : A3;
        Bbase = Bg + ((bz == 0) ? 2 * sB : (bz == 1) ? (size_t)0 : sB);
    } else {
        Abase = Ag + (size_t)bz * sA;
        Bbase = Bg + (size_t)bz * sB;
    }
    const uint16_t* Ab = Abase + (size_t)m0 * lda;  // PK panel base
    const uint16_t* Bb = Bbase + (size_t)n0 * ldb;
    const int tid = threadIdx.x, lane = tid & 63;
    const int wid = tid >> 6, wr = wid >> 2, wc = wid & 3;
    const int lr = lane & 15, lg = lane >> 4;
    const int lbase = lg * 128 + lr * 8;
    const size_t eldA = (size_t)lda * 16, eldB = (size_t)ldb * 16;

    f32x4 acc[8][4] = {};
    bf16x8 bfr[4][2];
    // prologue: A(0)->As[0], B(0)->Bs[0], A(1)->As[1]; vmcnt(4) drains
    // A(0)+B(0), leaves A(1) in flight.
    STG_A(0, 0, 0); STG_A(0, 0, 1);
    STG_B(0, 0, 0); STG_B(0, 0, 1);
    STG_A(1, 1, 0); STG_A(1, 1, 1);
    VM4;
    CFENCE;
    __builtin_amdgcn_s_barrier();
    CFENCE;
    int sa = 0, sa2 = 2, sb = 0;   // sa=kt%3, sa2=(kt+2)%3, sb=kt&1
    for (int kt = 0; kt < nk - 2; ++kt) {
        READ_B(sb);
        PH_FREE(sa, 0, STG_B(kt + 1, sb ^ 1, 0));
        PH_FREE(sa, 1, STG_B(kt + 1, sb ^ 1, 1));
        PH_FREE(sa, 2, STG_A(kt + 2, sa2, 0));
        PH_SYNC(sa, 3, STG_A(kt + 2, sa2, 1), VM4);
        sa = (sa == 2) ? 0 : sa + 1;
        sa2 = (sa2 == 2) ? 0 : sa2 + 1;
        sb ^= 1;
    }
    // kt = nk-2: stage last B only; drain everything for the final tile.
    READ_B(sb);
    PH_FREE(sa, 0, STG_B(nk - 1, sb ^ 1, 0));
    PH_FREE(sa, 1, STG_B(nk - 1, sb ^ 1, 1));
    PH_FREE(sa, 2, NOST);
    PH_SYNC(sa, 3, NOST, VM0);
    sa = (sa == 2) ? 0 : sa + 1;
    sb ^= 1;
    // kt = nk-1: no staging, no vm wait.
    READ_B(sb);
    PH_FREE(sa, 0, NOST);
    PH_FREE(sa, 1, NOST);
    PH_FREE(sa, 2, NOST);
    PH_SYNC(sa, 3, NOST, NOPW);

    if constexpr (MODE == 0) {
        uint16_t* C = (uint16_t*)Cg + (size_t)bz * sC;
#pragma unroll
        for (int i = 0; i < 8; i++) {
            const int gm = m0 + wr * 128 + i * 16 + lg * 4;   // gm&15 == lg*4
            const size_t pbase = (size_t)(gm >> 4) * (ldc / 8);
#pragma unroll
            for (int j = 0; j < 4; j++) {
                const int gn = n0 + wc * 64 + j * 16 + lr;
                const size_t off = (pbase + (gn >> 3)) * 128 + (gn & 7);
#pragma unroll
                for (int r = 0; r < 4; r++)
                    C[off + (lg * 4 + r) * 8] = f2bf(acc[i][j][r] * scale);
            }
        }
    } else if constexpr (MODE == 1) {
        uint16_t* C = (uint16_t*)Cg;
#pragma unroll
        for (int i = 0; i < 8; i++) {
            const int gm = m0 + wr * 128 + i * 16 + lg * 4;  // global m = b*SEQ + s
            const int bb = gm / SEQ;                         // uniform per block
            const int s0 = gm - bb * SEQ;                    // s0&7 in {0,4}
            uint16_t* Cb = C + (size_t)bb * DMODEL * SEQ;
#pragma unroll
            for (int j = 0; j < 4; j++) {
                const int e = n0 + wc * 64 + j * 16 + lr;
                const size_t off = ((size_t)(e >> 4) * (SEQ / 8) + (s0 >> 3)) * 128 +
                                   (e & 15) * 8 + (s0 & 7);
                u32x2 v = {pk2(acc[i][j][0], acc[i][j][1]), pk2(acc[i][j][2], acc[i][j][3])};
                *(u32x2*)&Cb[off] = v;
            }
        }
    } else if constexpr (MODE == 2) {
        float* C = (float*)Cg + (size_t)bz * sC;
        const float* LB = Linv + bz * SEQ;
#pragma unroll
        for (int i = 0; i < 8; i++) {
            const int gm = m0 + wr * 128 + i * 16 + lg * 4;
            const f32x4 lv = *(const f32x4*)&LB[gm];
#pragma unroll
            for (int j = 0; j < 4; j++) {
                const int gn = n0 + wc * 64 + j * 16 + lr;
#pragma unroll
                for (int r = 0; r < 4; r++)
                    C[(size_t)(gm + r) * ldc + gn] = acc[i][j][r] * lv[r];
            }
        }
    } else {  // MODE 3: merged projection epilogue
        if (bz < 2) {
            uint16_t* C = (uint16_t*)(bz == 0 ? Cg : C2);
            const float sc = bz == 0 ? scale : 1.0f;
#pragma unroll
            for (int i = 0; i < 8; i++) {
                const int gm = m0 + wr * 128 + i * 16 + lg * 4;
                const size_t pbase = (size_t)(gm >> 4) * (ldc / 8);
#pragma unroll
                for (int j = 0; j < 4; j++) {
                    const int gn = n0 + wc * 64 + j * 16 + lr;
                    const size_t off = (pbase + (gn >> 3)) * 128 + (gn & 7);
#pragma unroll
                    for (int r = 0; r < 4; r++)
                        C[off + (lg * 4 + r) * 8] = f2bf(acc[i][j][r] * sc);
                }
            }
        } else {
            uint16_t* C = (uint16_t*)C3;
#pragma unroll
            for (int i = 0; i < 8; i++) {
                const int gm = m0 + wr * 128 + i * 16 + lg * 4;
                const int bb = gm / SEQ;
                const int s0 = gm - bb * SEQ;
                uint16_t* Cb = C + (size_t)bb * DMODEL * SEQ;
#pragma unroll
                for (int j = 0; j < 4; j++) {
                    const int e = n0 + wc * 64 + j * 16 + lr;
                    const size_t off = ((size_t)(e >> 4) * (SEQ / 8) + (s0 >> 3)) * 128 +
                                       (e & 15) * 8 + (s0 & 7);
                    u32x2 v = {pk2(acc[i][j][0], acc[i][j][1]),
                               pk2(acc[i][j][2], acc[i][j][3])};
                    *(u32x2*)&Cb[off] = v;
                }
            }
        }
    }
}

// ---------------------------------------------------------------------------
// Kernel 3: row softmax on PK-layout S, in place.  One block per 16-row panel
// (contiguous 32KB).  Thread t owns row t&15, k-slots (t>>4)+16u, u=0..15.
// ---------------------------------------------------------------------------
__global__ __launch_bounds__(256) void softmax_pk(uint16_t* __restrict__ S,
                                                  float* __restrict__ Linv) {
    const size_t panel = blockIdx.x;
    uint16_t* sp = S + panel * (size_t)(16 * SEQ);
    const int t = threadIdx.x, lane = t & 63, w = t >> 6;
    const int r15 = t & 15, ksl = t >> 4;
    __shared__ float rm[4][16], rs[4][16];
    u32x4 raw[16];
    float mx = -3.0e38f;
#pragma unroll
    for (int u = 0; u < 16; u++) {
        raw[u] = *(const u32x4*)&sp[(ksl + u * 16) * 128 + r15 * 8];
#pragma unroll
        for (int j = 0; j < 4; j++) {
            mx = fmaxf(mx, __builtin_bit_cast(float, raw[u][j] << 16));
            mx = fmaxf(mx, __builtin_bit_cast(float, raw[u][j] & 0xffff0000u));
        }
    }
    mx = fmaxf(mx, __shfl_xor(mx, 16));
    mx = fmaxf(mx, __shfl_xor(mx, 32));
    if (lane < 16) rm[w][lane] = mx;
    __syncthreads();
    const float m = fmaxf(fmaxf(rm[0][r15], rm[1][r15]), fmaxf(rm[2][r15], rm[3][r15]));
    float sum = 0.0f;
#pragma unroll
    for (int u = 0; u < 16; u++) {
#pragma unroll
        for (int j = 0; j < 4; j++) {
            float lo = __expf(__builtin_bit_cast(float, raw[u][j] << 16) - m);
            float hi = __expf(__builtin_bit_cast(float, raw[u][j] & 0xffff0000u) - m);
            sum += lo + hi;
            raw[u][j] = pk2(lo, hi);
        }
    }
    sum += __shfl_xor(sum, 16);
    sum += __shfl_xor(sum, 32);
    if (lane < 16) rs[w][lane] = sum;
    __syncthreads();
    const float tot = rs[0][r15] + rs[1][r15] + rs[2][r15] + rs[3][r15];
#pragma unroll
    for (int u = 0; u < 16; u++)
        *(u32x4*)&sp[(ksl + u * 16) * 128 + r15 * 8] = raw[u];
    if (w == 0 && lane < 16) Linv[panel * 16 + lane] = 1.0f / tot;
}

// ---------------------------------------------------------------------------
// Buffer plan (aliasing-audited):
//   ws:  Qbf [0, 33.5M)  Kbf [33.5M, 67.1M)  VTb [67.1M, 100.7M)
//        WT  [100.7M, 106.95M)  Linv [106.95M, ~107M)
//        S/P [107,020,288 .. 174,129,152)
//   X casts (all DISJOINT, dead before their region is re-written):
//        XqB = d_out[0 .. 32M)            (PV writes all of d_out at the end)
//        XkB = S + 0       [107,020,288)  (scores writes S after proj done)
//        XvB = S + 33.5MB  [140,574,720)
//   Temporal chain: cast3 -> proj(reads X*, writes Q/K/VT) -> scores(clobbers
//   XkB/XvB) -> softmax -> PV(clobbers XqB, writes full out).
// ---------------------------------------------------------------------------
extern "C" void kernel_launch(void* const* d_in, const int* in_sizes, int n_in,
                              void* d_out, int out_size, void* d_ws, size_t ws_size,
                              hipStream_t stream) {
    const float* Xk = (const float*)d_in[0];
    const float* Xv = (const float*)d_in[1];
    const float* Xq = (const float*)d_in[2];
    const float* Wk = (const float*)d_in[3];
    const float* Wv = (const float*)d_in[4];
    const float* Wq = (const float*)d_in[5];
    float* out = (float*)d_out;
    char* ws = (char*)d_ws;
    uint16_t* Qbf = (uint16_t*)(ws);
    uint16_t* Kbf = (uint16_t*)(ws + (size_t)33554432);
    uint16_t* VTb = (uint16_t*)(ws + (size_t)67108864);
    uint16_t* WT  = (uint16_t*)(ws + (size_t)100663296);
    float*    Linv= (float*)(ws + (size_t)106954752);
    uint16_t* Sb  = (uint16_t*)(ws + (size_t)107020288);
    uint16_t* XqB = (uint16_t*)d_out;                        // 32 MB of 64 MB out
    uint16_t* XkB = Sb;                                      // S + 0
    uint16_t* XvB = (uint16_t*)(ws + (size_t)140574720);     // S + 32 MB

    wt_cast_kernel<<<dim3(32, 32, 3), dim3(32, 8), 0, stream>>>(Wk, Wv, Wq, WT);
    // all three input casts in one dispatch (disjoint destinations)
    cast3_bf16_pk<<<dim3(8192, 3), 256, 0, stream>>>(Xq, Xk, Xv, XqB, XkB, XvB);
    // merged Q/K/V projection: z=0 Q (scale 1/32), z=1 K, z=2 V (VT store)
    gemm8p<3, 0><<<dim3(64, 4, 3), 512, 0, stream>>>(
        XqB, WT, (void*)Qbf, nullptr, 0.03125f,
        DMODEL, DMODEL, DMODEL, DMODEL / 64,
        0, (size_t)1048576 /*WT stride*/, 0,
        XkB, XvB, (void*)Kbf, (void*)VTb);
    // scores: S[b][q][k] = Qhat[b] . K[b]^T  (bf16 PK store), XCD = batch
    gemm8p<0, 1><<<dim3(8, 8, 8), 512, 0, stream>>>(
        Qbf, Kbf, (void*)Sb, nullptr, 1.0f,
        DMODEL, DMODEL, SEQ, DMODEL / 64,
        (size_t)SEQ * DMODEL, (size_t)SEQ * DMODEL, (size_t)SEQ * SEQ,
        nullptr, nullptr, nullptr, nullptr);
    // in-place row softmax -> P, Linv
    softmax_pk<<<dim3(BATCH * SEQ / 16), 256, 0, stream>>>(Sb, Linv);
    // Z[b][q][e] = (P[b] . V[b]) * Linv  (f32 plain store)
    gemm8p<2, 1><<<dim3(8, 8, 4), 512, 0, stream>>>(
        Sb, VTb, (void*)out, Linv, 1.0f,
        SEQ, SEQ, DMODEL, SEQ / 64,
        (size_t)SEQ * SEQ, (size_t)DMODEL * SEQ, (size_t)SEQ * DMODEL,
        nullptr, nullptr, nullptr, nullptr);
}